// Round 5
// baseline (4096.381 us; speedup 1.0000x reference)
//
#include <hip/hip_runtime.h>
#include <math.h>

#define M_SEQ 11520   // B*N
#define CHUNK 3840    // M-chunk for GRU stack (3 chunks) -> ws ~= 32 MB total
#define NNODE 360
#define NB    32
#define TT    64

// accurate transcendentals until green (argmax near-ties are precision-fragile)
__device__ __forceinline__ float fsig(float x)  { return 1.0f / (1.0f + expf(-x)); }
__device__ __forceinline__ float ftanh(float x) { return tanhf(x); }

// ---------------- JAX threefry2x32, key = (0, 42) ---------------------------
__device__ __forceinline__ unsigned rotl32(unsigned x, int n) { return (x << n) | (x >> (32 - n)); }

__device__ __forceinline__ void tf2x32(unsigned& x0, unsigned& x1)
{
    const unsigned k0 = 0u, k1 = 42u, k2 = 0u ^ 42u ^ 0x1BD11BDAu;
    x0 += k0; x1 += k1;
#define R4(a,b,c,d) \
    x0 += x1; x1 = rotl32(x1,a); x1 ^= x0; \
    x0 += x1; x1 = rotl32(x1,b); x1 ^= x0; \
    x0 += x1; x1 = rotl32(x1,c); x1 ^= x0; \
    x0 += x1; x1 = rotl32(x1,d); x1 ^= x0;
    R4(13,15,26,6)   x0 += k1; x1 += k2 + 1u;
    R4(17,29,16,24)  x0 += k2; x1 += k0 + 2u;
    R4(13,15,26,6)   x0 += k0; x1 += k1 + 3u;
    R4(17,29,16,24)  x0 += k1; x1 += k2 + 4u;
    R4(13,15,26,6)   x0 += k2; x1 += k0 + 5u;
#undef R4
}

// RNG variant ledger (absmax 3.753662e-3 = "wrong graph" signature):
//   R1/R4: partitionable, bits = y1            -> FAILED
//   R2:    legacy split-half concat            -> FAILED
//   NOW:   partitionable, bits = y0 ^ y1       <- jax _threefry_random_bits_
//          partitionable returns bits1 ^ bits2 for bit_width in {8,16,32}
#define RNG_VARIANT 2   // 0=legacy, 1=part-y1, 2=part-xor

__device__ __forceinline__ float jax_uniform(unsigned idx)
{
#if RNG_VARIANT == 0
    const unsigned half = 2073600u;   // (32*360*360)/2
    unsigned a0, a1;
    if (idx < half) { a0 = idx;        a1 = idx + half; }
    else            { a0 = idx - half; a1 = idx;        }
    tf2x32(a0, a1);
    unsigned bits = (idx < half) ? a0 : a1;
#elif RNG_VARIANT == 1
    unsigned x0 = 0u, x1 = idx;
    tf2x32(x0, x1);
    unsigned bits = x1;
#else
    unsigned x0 = 0u, x1 = idx;       // counts_hi = 0 (idx < 2^32), counts_lo = idx
    tf2x32(x0, x1);
    unsigned bits = x0 ^ x1;          // jax: bits1 ^ bits2 for 32-bit output
#endif
    return __uint_as_float((bits >> 9) | 0x3f800000u) - 1.0f;
}

// ---------------- bidirectional GRU layer on an M-chunk ---------------------
// x: (nrows, 64, I) contiguous.  out: (nrows, 64, 16), dir writes its 8-half.
template<int I>
__global__ void gru_layer(const float* __restrict__ x,
                          const float* __restrict__ wih,  // (2, 24, I)
                          const float* __restrict__ whh,  // (2, 24, 8)
                          const float* __restrict__ bih,  // (2, 24)
                          const float* __restrict__ bhh,  // (2, 24)
                          float* __restrict__ out, int nrows)
{
    const int dir = blockIdx.y;
    const int m   = blockIdx.x * blockDim.x + threadIdx.x;
    if (m >= nrows) return;
    const float* Wih = wih + dir * 24 * I;
    const float* Whh = whh + dir * 24 * 8;
    const float* Bih = bih + dir * 24;
    const float* Bhh = bhh + dir * 24;
    const float* xm  = x   + (size_t)m * TT * I;
    float*       om  = out + (size_t)m * TT * 16 + dir * 8;

    float h[8];
#pragma unroll
    for (int j = 0; j < 8; ++j) h[j] = 0.f;

    for (int tt = 0; tt < TT; ++tt) {
        const int t = dir ? (TT - 1 - tt) : tt;
        float xv[I];
        const float4* xp4 = reinterpret_cast<const float4*>(xm + t * I);
#pragma unroll
        for (int q = 0; q < I / 4; ++q) {
            float4 f = xp4[q];
            xv[4*q] = f.x; xv[4*q+1] = f.y; xv[4*q+2] = f.z; xv[4*q+3] = f.w;
        }
        float xg[24], gh[24];
#pragma unroll
        for (int g = 0; g < 24; ++g) {
            float a = 0.f;
#pragma unroll
            for (int i = 0; i < I; ++i) a += xv[i] * Wih[g * I + i];
            xg[g] = a + Bih[g];
            float bsum = 0.f;
#pragma unroll
            for (int j = 0; j < 8; ++j) bsum += h[j] * Whh[g * 8 + j];
            gh[g] = bsum + Bhh[g];
        }
#pragma unroll
        for (int j = 0; j < 8; ++j) {
            float r  = fsig(xg[j]      + gh[j]);
            float z  = fsig(xg[8 + j]  + gh[8 + j]);
            float nn = ftanh(xg[16 + j] + r * gh[16 + j]);
            h[j] = (1.f - z) * nn + z * h[j];
        }
        float4* o4 = reinterpret_cast<float4*>(om + t * 16);
        o4[0] = make_float4(h[0], h[1], h[2], h[3]);
        o4[1] = make_float4(h[4], h[5], h[6], h[7]);
    }
}

// ---------------- feat MLP on an M-chunk ------------------------------------
__global__ void feat_kernel(const float* __restrict__ gout,
                            const float* __restrict__ l1w, const float* __restrict__ l1b,
                            const float* __restrict__ l2w, const float* __restrict__ l2b,
                            float* __restrict__ feat, int nrows)
{
    int m = blockIdx.x * blockDim.x + threadIdx.x;
    if (m >= nrows) return;
    const float* xp = gout + (size_t)m * TT * 16 + (TT - 1) * 16;
    float xv[16];
#pragma unroll
    for (int i = 0; i < 16; ++i) xv[i] = xp[i];
    float h1[8];
#pragma unroll
    for (int o = 0; o < 8; ++o) {
        float a = 0.f;
#pragma unroll
        for (int f = 0; f < 16; ++f) a += xv[f] * l1w[o * 16 + f];
        a += l1b[o];
        h1[o] = (a >= 0.f) ? a : 0.2f * a;
    }
#pragma unroll
    for (int o = 0; o < 8; ++o) {
        float a = 0.f;
#pragma unroll
        for (int f = 0; f < 8; ++f) a += h1[f] * l2w[o * 8 + f];
        feat[(size_t)m * 8 + o] = a + l2b[o];
    }
}

// ---------------- adjacency: per row -> (argmax col, adj value v) -----------
// adj = y_soft + (y_hard - y_soft): off-argmax entries are EXACTLY zero in
// fp32, so adj has one nonzero per row; zeroed if argmax == diagonal.
__global__ void adj_kernel(const float* __restrict__ feat,
                           const float* __restrict__ tptr,
                           int* __restrict__ colp, float* __restrict__ vp)
{
    const int gw   = (blockIdx.x * blockDim.x + threadIdx.x) >> 6;
    const int lane = threadIdx.x & 63;
    if (gw >= NB * NNODE) return;
    const int b = gw / NNODE;
    const int n = gw - b * NNODE;
    const float T = tptr[0];
    const float* fb = feat + (size_t)b * NNODE * 8;
    float fn[8];
#pragma unroll
    for (int k = 0; k < 8; ++k) fn[k] = fb[(size_t)n * 8 + k];

    float sv[6];
    float mval = -3.0e38f; int midx = 1 << 30;
#pragma unroll
    for (int s = 0; s < 6; ++s) {
        int p = s * 64 + lane;
        float xs = -3.0e38f;
        if (p < NNODE) {
            const float* fp = fb + (size_t)p * 8;
            float d = 0.f;
#pragma unroll
            for (int k = 0; k < 8; ++k) d += fn[k] * fp[k];
            unsigned idx = (unsigned)gw * 360u + (unsigned)p;
            float u   = jax_uniform(idx);
            float gum = -logf(-logf(u + 1e-10f) + 1e-10f);
            xs = (d + gum) / T;
            if (xs > mval) { mval = xs; midx = p; }   // ascending p: first-max kept
        }
        sv[s] = xs;
    }
    for (int off = 32; off > 0; off >>= 1) {   // ties -> smaller index (np.argmax)
        float ov = __shfl_xor(mval, off);
        int   oi = __shfl_xor(midx, off);
        if (ov > mval || (ov == mval && oi < midx)) { mval = ov; midx = oi; }
    }
    float ssum = 0.f;
#pragma unroll
    for (int s = 0; s < 6; ++s) {
        int p = s * 64 + lane;
        if (p < NNODE) ssum += expf(sv[s] - mval);
    }
    for (int off = 32; off > 0; off >>= 1) ssum += __shfl_xor(ssum, off);
    if (lane == 0) {
        float ys = 1.0f / ssum;           // y_soft at the argmax
        float v  = ys + (1.0f - ys);      // y_soft + (y_hard - y_soft), fp-exact
        if (midx == n) v = 0.0f;          // diagonal zeroed
        colp[gw] = midx;
        vp[gw]   = v;
    }
}

// ---------------- DCGRU 3-layer step (encoder & decoder) --------------------
// adj@x collapses to gathers: x1[n] = v_n*x[c1], x2[n] = vv_n*x[c2] - x[n],
// vv = 2*v_n*v_{c1}.
__device__ __forceinline__ void run3(float (*s_h)[NNODE], float* s_o, float* s_rh,
                                     const float* Wg, const float* Bg,
                                     const float* Wc, const float* Bc,
                                     bool act, int n, int c1, int c2,
                                     float v, float vv, float& olast)
{
    for (int l = 0; l < 3; ++l) {
        __syncthreads();   // o[] / h[l][] ready for gathers
        float on = 0, oc1 = 0, oc2 = 0, hn = 0, hc1 = 0, hc2 = 0;
        if (act) {
            on = s_o[n]; oc1 = s_o[c1]; oc2 = s_o[c2];
            hn = s_h[l][n]; hc1 = s_h[l][c1]; hc2 = s_h[l][c2];
        }
        float f0 = on, f1 = v * oc1, f2 = vv * oc2 - on;
        float f3 = hn, f4 = v * hc1, f5 = vv * hc2 - hn;
        const float* W = &Wg[l * 12];
        float r = fsig(f0*W[0] + f1*W[2] + f2*W[4] + f3*W[6] + f4*W[8] + f5*W[10] + Bg[l*2]);
        float u = fsig(f0*W[1] + f1*W[3] + f2*W[5] + f3*W[7] + f4*W[9] + f5*W[11] + Bg[l*2+1]);
        float rhn = r * hn;
        if (act) s_rh[n] = rhn;
        __syncthreads();   // rh ready; o/h gathers above are also done
        float rhc1 = 0, rhc2 = 0;
        if (act) { rhc1 = s_rh[c1]; rhc2 = s_rh[c2]; }
        const float* C = &Wc[l * 6];
        float cc = ftanh(f0*C[0] + f1*C[1] + f2*C[2]
                         + rhn*C[3] + (v*rhc1)*C[4] + (vv*rhc2 - rhn)*C[5] + Bc[l]);
        float hnew = u * hn + (1.0f - u) * cc;
        if (act) { s_h[l][n] = hnew; s_o[n] = hnew; }  // post-sync reads touch rh only
        olast = hnew;
    }
}

__global__ __launch_bounds__(384) void decode_kernel(
    const float* __restrict__ rec,   // (B, N, T)
    const int*   __restrict__ colp, const float* __restrict__ vp,
    const float* __restrict__ egw, const float* __restrict__ egb,
    const float* __restrict__ ecw, const float* __restrict__ ecb,
    const float* __restrict__ dgw, const float* __restrict__ dgb,
    const float* __restrict__ dcw, const float* __restrict__ dcb,
    const float* __restrict__ pw,  const float* __restrict__ pb,
    float* __restrict__ outp)        // (B, N, T)
{
    __shared__ float s_h[3][NNODE];
    __shared__ float s_o[NNODE];
    __shared__ float s_rh[NNODE];
    __shared__ float s_v[NNODE];
    __shared__ int   s_c[NNODE];
    __shared__ float s_egw[36], s_egb[6], s_ecw[18], s_ecb[3];
    __shared__ float s_dgw[36], s_dgb[6], s_dcw[18], s_dcb[3];

    const int b = blockIdx.x;
    const int n = threadIdx.x;
    if (n < 36) { s_egw[n] = egw[n]; s_dgw[n] = dgw[n]; }
    if (n < 6)  { s_egb[n] = egb[n]; s_dgb[n] = dgb[n]; }
    if (n < 18) { s_ecw[n] = ecw[n]; s_dcw[n] = dcw[n]; }
    if (n < 3)  { s_ecb[n] = ecb[n]; s_dcb[n] = dcb[n]; }
    const bool act = n < NNODE;
    if (act) {
        s_c[n] = colp[b * NNODE + n];
        s_v[n] = vp[b * NNODE + n];
        s_h[0][n] = 0.f; s_h[1][n] = 0.f; s_h[2][n] = 0.f;
    }
    __syncthreads();
    int c1 = 0, c2 = 0; float v = 0.f, vv = 0.f;
    if (act) {
        c1 = s_c[n];
        c2 = s_c[c1];                 // two-hop column
        v  = s_v[n];
        vv = 2.0f * v * s_v[c1];
    }
    const float projw = pw[0], projb = pb[0];

    for (int t = 0; t < TT; ++t) {   // encoder over rec[:, :, t]
        if (act) s_o[n] = rec[((size_t)b * NNODE + n) * TT + t];
        float olast;
        run3(s_h, s_o, s_rh, s_egw, s_egb, s_ecw, s_ecb, act, n, c1, c2, v, vv, olast);
    }
    float inp = 0.f;
    for (int t = 0; t < TT; ++t) {   // decoder, feedback = proj
        if (act) s_o[n] = inp;
        float olast = 0.f;
        run3(s_h, s_o, s_rh, s_dgw, s_dgb, s_dcw, s_dcb, act, n, c1, c2, v, vv, olast);
        float proj = olast * projw + projb;
        if (act) outp[((size_t)b * NNODE + n) * TT + t] = proj;
        inp = proj;
    }
}

// ---------------- host launcher ---------------------------------------------
extern "C" void kernel_launch(void* const* d_in, const int* in_sizes, int n_in,
                              void* d_out, int out_size, void* d_ws, size_t ws_size,
                              hipStream_t stream)
{
    (void)in_sizes; (void)n_in; (void)out_size; (void)ws_size;
    const float* full_seq = (const float*)d_in[0];   // (32,360,512) = (M,64,8)
    const float* rec_seq  = (const float*)d_in[1];   // (32,360,64)
    const float* temp     = (const float*)d_in[3];
    const float* g0wih    = (const float*)d_in[4];
    const float* g0whh    = (const float*)d_in[5];
    const float* g0bih    = (const float*)d_in[6];
    const float* g0bhh    = (const float*)d_in[7];
    const float* gwih     = (const float*)d_in[8];   // (3,2,24,16)
    const float* gwhh     = (const float*)d_in[9];   // (3,2,24,8)
    const float* gbih     = (const float*)d_in[10];
    const float* gbhh     = (const float*)d_in[11];
    const float* l1w      = (const float*)d_in[12];
    const float* l1b      = (const float*)d_in[13];
    const float* l2w      = (const float*)d_in[14];
    const float* l2b      = (const float*)d_in[15];
    const float* enc_gw   = (const float*)d_in[16];
    const float* enc_gb   = (const float*)d_in[17];
    const float* enc_cw   = (const float*)d_in[18];
    const float* enc_cb   = (const float*)d_in[19];
    const float* dec_gw   = (const float*)d_in[20];
    const float* dec_gb   = (const float*)d_in[21];
    const float* dec_cw   = (const float*)d_in[22];
    const float* dec_cb   = (const float*)d_in[23];
    const float* proj_w   = (const float*)d_in[24];
    const float* proj_b   = (const float*)d_in[25];
    float* outp = (float*)d_out;

    // ws layout, small-first; GRU stack chunked in M to keep footprint ~32 MB
    float* ws   = (float*)d_ws;
    float* feat = ws;                                     // (M,8)
    float* vbuf = feat + (size_t)M_SEQ * 8;               // (M,)
    int*   cbuf = (int*)(vbuf + M_SEQ);                   // (M,)
    float* bufA = (float*)(cbuf + M_SEQ);                 // (CHUNK,64,16)
    float* bufB = bufA + (size_t)CHUNK * TT * 16;         // (CHUNK,64,16)

    const dim3 gg(CHUNK / 256, 2);
    for (int cs = 0; cs < M_SEQ; cs += CHUNK) {
        const float* x0 = full_seq + (size_t)cs * TT * 8;
        gru_layer<8><<<gg, 256, 0, stream>>>(x0, g0wih, g0whh, g0bih, g0bhh, bufA, CHUNK);
        gru_layer<16><<<gg, 256, 0, stream>>>(bufA, gwih + 0 * 768, gwhh + 0 * 384,
                                              gbih + 0 * 48, gbhh + 0 * 48, bufB, CHUNK);
        gru_layer<16><<<gg, 256, 0, stream>>>(bufB, gwih + 1 * 768, gwhh + 1 * 384,
                                              gbih + 1 * 48, gbhh + 1 * 48, bufA, CHUNK);
        gru_layer<16><<<gg, 256, 0, stream>>>(bufA, gwih + 2 * 768, gwhh + 2 * 384,
                                              gbih + 2 * 48, gbhh + 2 * 48, bufB, CHUNK);
        feat_kernel<<<CHUNK / 256, 256, 0, stream>>>(bufB, l1w, l1b, l2w, l2b,
                                                     feat + (size_t)cs * 8, CHUNK);
    }
    adj_kernel<<<(NB * NNODE) / 4, 256, 0, stream>>>(feat, temp, cbuf, vbuf);
    decode_kernel<<<NB, 384, 0, stream>>>(rec_seq, cbuf, vbuf,
                                          enc_gw, enc_gb, enc_cw, enc_cb,
                                          dec_gw, dec_gb, dec_cw, dec_cb,
                                          proj_w, proj_b, outp);
}

// Round 6
// 1115.162 us; speedup vs baseline: 3.6734x; 3.6734x over previous
//
#include <hip/hip_runtime.h>
#include <math.h>

#define M_SEQ 11520   // B*N
#define CHUNK 3840    // M-chunk: ws = 2*15.7MB bufs + 47.2MB xg ~= 79MB (<95MB proven)
#define NNODE 360
#define NB    32
#define TT    64

// libm-accurate transcendentals: argmax near-ties are precision-fragile and
// current margin is 6x threshold — don't spend it on __expf.
__device__ __forceinline__ float fsig(float x)  { return 1.0f / (1.0f + expf(-x)); }
__device__ __forceinline__ float ftanh(float x) { return tanhf(x); }

// ---------------- JAX threefry2x32, key=(0,42), partitionable, bits=y0^y1 ----
__device__ __forceinline__ unsigned rotl32(unsigned x, int n) { return (x << n) | (x >> (32 - n)); }

__device__ __forceinline__ void tf2x32(unsigned& x0, unsigned& x1)
{
    const unsigned k0 = 0u, k1 = 42u, k2 = 0u ^ 42u ^ 0x1BD11BDAu;
    x0 += k0; x1 += k1;
#define R4(a,b,c,d) \
    x0 += x1; x1 = rotl32(x1,a); x1 ^= x0; \
    x0 += x1; x1 = rotl32(x1,b); x1 ^= x0; \
    x0 += x1; x1 = rotl32(x1,c); x1 ^= x0; \
    x0 += x1; x1 = rotl32(x1,d); x1 ^= x0;
    R4(13,15,26,6)   x0 += k1; x1 += k2 + 1u;
    R4(17,29,16,24)  x0 += k2; x1 += k0 + 2u;
    R4(13,15,26,6)   x0 += k0; x1 += k1 + 3u;
    R4(17,29,16,24)  x0 += k1; x1 += k2 + 4u;
    R4(13,15,26,6)   x0 += k2; x1 += k0 + 5u;
#undef R4
}

__device__ __forceinline__ float jax_uniform(unsigned idx)
{
    unsigned x0 = 0u, x1 = idx;       // counts_hi=0, counts_lo=idx
    tf2x32(x0, x1);
    unsigned bits = x0 ^ x1;          // jax partitionable: bits1 ^ bits2 (VERIFIED R5)
    return __uint_as_float((bits >> 9) | 0x3f800000u) - 1.0f;
}

// ---------------- GRU phase 1: xg[m,dir,t,24] = x[m,t,:]·Wih^T + bih --------
// Time-parallel (outside the scan). One thread per (m,t); blockIdx.y = dir.
template<int I>
__global__ void gru_xg(const float* __restrict__ x,
                       const float* __restrict__ wih,  // (2,24,I)
                       const float* __restrict__ bih,  // (2,24)
                       float* __restrict__ xg, int nrows)
{
    const int dir = blockIdx.y;
    __shared__ float sW[24 * I];
    __shared__ float sB[24];
    for (int i = threadIdx.x; i < 24 * I; i += 256) sW[i] = wih[dir * 24 * I + i];
    if (threadIdx.x < 24) sB[threadIdx.x] = bih[dir * 24 + threadIdx.x];
    __syncthreads();
    const int gid = blockIdx.x * 256 + threadIdx.x;   // m*64 + t
    if (gid >= nrows * TT) return;
    const int m = gid >> 6, t = gid & 63;
    float xv[I];
    const float4* xp4 = reinterpret_cast<const float4*>(x + (size_t)gid * I);
#pragma unroll
    for (int q = 0; q < I / 4; ++q) {
        float4 f = xp4[q];
        xv[4*q] = f.x; xv[4*q+1] = f.y; xv[4*q+2] = f.z; xv[4*q+3] = f.w;
    }
    float* og = xg + (((size_t)(m * 2 + dir)) * TT + t) * 24;
#pragma unroll
    for (int g = 0; g < 24; ++g) {
        float a = sB[g];
#pragma unroll
        for (int i = 0; i < I; ++i) a += xv[i] * sW[g * I + i];   // sW: broadcast read
        og[g] = a;
    }
}

// ---------------- GRU phase 2: the 64-step recurrence -----------------------
// 8 lanes per (m,dir); lane j owns h[j] + its 3 Whh gate rows in VGPRs;
// h[0..7] broadcast via __shfl each step. Serial work/step: 24 FMA + 3 exp.
__global__ void gru_rec(const float* __restrict__ xg,   // (nrows,2,64,24)
                        const float* __restrict__ whh,  // (2,24,8)
                        const float* __restrict__ bhh,  // (2,24)
                        float* __restrict__ out, int nrows)  // (nrows,64,16)
{
    const int tid = blockIdx.x * 256 + threadIdx.x;
    const int j   = tid & 7;
    const int md  = tid >> 3;             // m*2 + dir
    if (md >= nrows * 2) return;
    const int m = md >> 1, dir = md & 1;
    const int lane_base = (threadIdx.x & 63) & ~7;

    float w0[8], w1[8], w2[8];
    const float* W = whh + dir * 192;
#pragma unroll
    for (int k = 0; k < 8; ++k) {
        w0[k] = W[j * 8 + k];
        w1[k] = W[(8 + j) * 8 + k];
        w2[k] = W[(16 + j) * 8 + k];
    }
    const float b0 = bhh[dir * 24 + j];
    const float b1 = bhh[dir * 24 + 8 + j];
    const float b2 = bhh[dir * 24 + 16 + j];

    const float* xgm = xg + (size_t)md * TT * 24;
    float* om = out + (size_t)m * TT * 16 + dir * 8 + j;

    float h = 0.f;
    for (int tt = 0; tt < TT; ++tt) {
        const int t = dir ? (TT - 1 - tt) : tt;
        const float* xp = xgm + t * 24;
        float xr = xp[j], xz = xp[8 + j], xn = xp[16 + j];
        float gh0 = b0, gh1 = b1, gh2 = b2;
#pragma unroll
        for (int k = 0; k < 8; ++k) {
            float hk = __shfl(h, lane_base + k, 64);
            gh0 += hk * w0[k];
            gh1 += hk * w1[k];
            gh2 += hk * w2[k];
        }
        float r  = fsig(xr + gh0);
        float z  = fsig(xz + gh1);
        float nn = ftanh(xn + r * gh2);
        h = (1.f - z) * nn + z * h;
        om[t * 16] = h;
    }
}

// ---------------- feat MLP on an M-chunk ------------------------------------
__global__ void feat_kernel(const float* __restrict__ gout,
                            const float* __restrict__ l1w, const float* __restrict__ l1b,
                            const float* __restrict__ l2w, const float* __restrict__ l2b,
                            float* __restrict__ feat, int nrows)
{
    int m = blockIdx.x * blockDim.x + threadIdx.x;
    if (m >= nrows) return;
    const float* xp = gout + (size_t)m * TT * 16 + (TT - 1) * 16;
    float xv[16];
#pragma unroll
    for (int i = 0; i < 16; ++i) xv[i] = xp[i];
    float h1[8];
#pragma unroll
    for (int o = 0; o < 8; ++o) {
        float a = 0.f;
#pragma unroll
        for (int f = 0; f < 16; ++f) a += xv[f] * l1w[o * 16 + f];
        a += l1b[o];
        h1[o] = (a >= 0.f) ? a : 0.2f * a;
    }
#pragma unroll
    for (int o = 0; o < 8; ++o) {
        float a = 0.f;
#pragma unroll
        for (int f = 0; f < 8; ++f) a += h1[f] * l2w[o * 8 + f];
        feat[(size_t)m * 8 + o] = a + l2b[o];
    }
}

// ---------------- adjacency: per row -> (argmax col, adj value v) -----------
__global__ void adj_kernel(const float* __restrict__ feat,
                           const float* __restrict__ tptr,
                           int* __restrict__ colp, float* __restrict__ vp)
{
    const int gw   = (blockIdx.x * blockDim.x + threadIdx.x) >> 6;
    const int lane = threadIdx.x & 63;
    if (gw >= NB * NNODE) return;
    const int b = gw / NNODE;
    const int n = gw - b * NNODE;
    const float T = tptr[0];
    const float* fb = feat + (size_t)b * NNODE * 8;
    float fn[8];
#pragma unroll
    for (int k = 0; k < 8; ++k) fn[k] = fb[(size_t)n * 8 + k];

    float sv[6];
    float mval = -3.0e38f; int midx = 1 << 30;
#pragma unroll
    for (int s = 0; s < 6; ++s) {
        int p = s * 64 + lane;
        float xs = -3.0e38f;
        if (p < NNODE) {
            const float* fp = fb + (size_t)p * 8;
            float d = 0.f;
#pragma unroll
            for (int k = 0; k < 8; ++k) d += fn[k] * fp[k];
            unsigned idx = (unsigned)gw * 360u + (unsigned)p;
            float u   = jax_uniform(idx);
            float gum = -logf(-logf(u + 1e-10f) + 1e-10f);
            xs = (d + gum) / T;
            if (xs > mval) { mval = xs; midx = p; }
        }
        sv[s] = xs;
    }
    for (int off = 32; off > 0; off >>= 1) {   // ties -> smaller index
        float ov = __shfl_xor(mval, off);
        int   oi = __shfl_xor(midx, off);
        if (ov > mval || (ov == mval && oi < midx)) { mval = ov; midx = oi; }
    }
    float ssum = 0.f;
#pragma unroll
    for (int s = 0; s < 6; ++s) {
        int p = s * 64 + lane;
        if (p < NNODE) ssum += expf(sv[s] - mval);
    }
    for (int off = 32; off > 0; off >>= 1) ssum += __shfl_xor(ssum, off);
    if (lane == 0) {
        float ys = 1.0f / ssum;
        float v  = ys + (1.0f - ys);
        if (midx == n) v = 0.0f;
        colp[gw] = midx;
        vp[gw]   = v;
    }
}

// ---------------- DCGRU 3-layer step (encoder & decoder) --------------------
__device__ __forceinline__ void run3(float (*s_h)[NNODE], float* s_o, float* s_rh,
                                     const float* Wg, const float* Bg,
                                     const float* Wc, const float* Bc,
                                     bool act, int n, int c1, int c2,
                                     float v, float vv, float& olast)
{
    for (int l = 0; l < 3; ++l) {
        __syncthreads();
        float on = 0, oc1 = 0, oc2 = 0, hn = 0, hc1 = 0, hc2 = 0;
        if (act) {
            on = s_o[n]; oc1 = s_o[c1]; oc2 = s_o[c2];
            hn = s_h[l][n]; hc1 = s_h[l][c1]; hc2 = s_h[l][c2];
        }
        float f0 = on, f1 = v * oc1, f2 = vv * oc2 - on;
        float f3 = hn, f4 = v * hc1, f5 = vv * hc2 - hn;
        const float* W = &Wg[l * 12];
        float r = fsig(f0*W[0] + f1*W[2] + f2*W[4] + f3*W[6] + f4*W[8] + f5*W[10] + Bg[l*2]);
        float u = fsig(f0*W[1] + f1*W[3] + f2*W[5] + f3*W[7] + f4*W[9] + f5*W[11] + Bg[l*2+1]);
        float rhn = r * hn;
        if (act) s_rh[n] = rhn;
        __syncthreads();
        float rhc1 = 0, rhc2 = 0;
        if (act) { rhc1 = s_rh[c1]; rhc2 = s_rh[c2]; }
        const float* C = &Wc[l * 6];
        float cc = ftanh(f0*C[0] + f1*C[1] + f2*C[2]
                         + rhn*C[3] + (v*rhc1)*C[4] + (vv*rhc2 - rhn)*C[5] + Bc[l]);
        float hnew = u * hn + (1.0f - u) * cc;
        if (act) { s_h[l][n] = hnew; s_o[n] = hnew; }
        olast = hnew;
    }
}

__global__ __launch_bounds__(384) void decode_kernel(
    const float* __restrict__ rec,
    const int*   __restrict__ colp, const float* __restrict__ vp,
    const float* __restrict__ egw, const float* __restrict__ egb,
    const float* __restrict__ ecw, const float* __restrict__ ecb,
    const float* __restrict__ dgw, const float* __restrict__ dgb,
    const float* __restrict__ dcw, const float* __restrict__ dcb,
    const float* __restrict__ pw,  const float* __restrict__ pb,
    float* __restrict__ outp)
{
    __shared__ float s_h[3][NNODE];
    __shared__ float s_o[NNODE];
    __shared__ float s_rh[NNODE];
    __shared__ float s_v[NNODE];
    __shared__ int   s_c[NNODE];
    __shared__ float s_egw[36], s_egb[6], s_ecw[18], s_ecb[3];
    __shared__ float s_dgw[36], s_dgb[6], s_dcw[18], s_dcb[3];

    const int b = blockIdx.x;
    const int n = threadIdx.x;
    if (n < 36) { s_egw[n] = egw[n]; s_dgw[n] = dgw[n]; }
    if (n < 6)  { s_egb[n] = egb[n]; s_dgb[n] = dgb[n]; }
    if (n < 18) { s_ecw[n] = ecw[n]; s_dcw[n] = dcw[n]; }
    if (n < 3)  { s_ecb[n] = ecb[n]; s_dcb[n] = dcb[n]; }
    const bool act = n < NNODE;
    if (act) {
        s_c[n] = colp[b * NNODE + n];
        s_v[n] = vp[b * NNODE + n];
        s_h[0][n] = 0.f; s_h[1][n] = 0.f; s_h[2][n] = 0.f;
    }
    __syncthreads();
    int c1 = 0, c2 = 0; float v = 0.f, vv = 0.f;
    if (act) {
        c1 = s_c[n];
        c2 = s_c[c1];
        v  = s_v[n];
        vv = 2.0f * v * s_v[c1];
    }
    const float projw = pw[0], projb = pb[0];

    for (int t = 0; t < TT; ++t) {
        if (act) s_o[n] = rec[((size_t)b * NNODE + n) * TT + t];
        float olast;
        run3(s_h, s_o, s_rh, s_egw, s_egb, s_ecw, s_ecb, act, n, c1, c2, v, vv, olast);
    }
    float inp = 0.f;
    for (int t = 0; t < TT; ++t) {
        if (act) s_o[n] = inp;
        float olast = 0.f;
        run3(s_h, s_o, s_rh, s_dgw, s_dgb, s_dcw, s_dcb, act, n, c1, c2, v, vv, olast);
        float proj = olast * projw + projb;
        if (act) outp[((size_t)b * NNODE + n) * TT + t] = proj;
        inp = proj;
    }
}

// ---------------- host launcher ---------------------------------------------
extern "C" void kernel_launch(void* const* d_in, const int* in_sizes, int n_in,
                              void* d_out, int out_size, void* d_ws, size_t ws_size,
                              hipStream_t stream)
{
    (void)in_sizes; (void)n_in; (void)out_size; (void)ws_size;
    const float* full_seq = (const float*)d_in[0];   // (M,64,8)
    const float* rec_seq  = (const float*)d_in[1];   // (32,360,64)
    const float* temp     = (const float*)d_in[3];
    const float* g0wih    = (const float*)d_in[4];
    const float* g0whh    = (const float*)d_in[5];
    const float* g0bih    = (const float*)d_in[6];
    const float* g0bhh    = (const float*)d_in[7];
    const float* gwih     = (const float*)d_in[8];   // (3,2,24,16)
    const float* gwhh     = (const float*)d_in[9];   // (3,2,24,8)
    const float* gbih     = (const float*)d_in[10];
    const float* gbhh     = (const float*)d_in[11];
    const float* l1w      = (const float*)d_in[12];
    const float* l1b      = (const float*)d_in[13];
    const float* l2w      = (const float*)d_in[14];
    const float* l2b      = (const float*)d_in[15];
    const float* enc_gw   = (const float*)d_in[16];
    const float* enc_gb   = (const float*)d_in[17];
    const float* enc_cw   = (const float*)d_in[18];
    const float* enc_cb   = (const float*)d_in[19];
    const float* dec_gw   = (const float*)d_in[20];
    const float* dec_gb   = (const float*)d_in[21];
    const float* dec_cw   = (const float*)d_in[22];
    const float* dec_cb   = (const float*)d_in[23];
    const float* proj_w   = (const float*)d_in[24];
    const float* proj_b   = (const float*)d_in[25];
    float* outp = (float*)d_out;

    // ws: small-first; per-chunk bufA/bufB (15.7MB each) + xg (47.2MB) ~= 79MB
    float* ws    = (float*)d_ws;
    float* feat  = ws;                                    // (M,8)
    float* vbuf  = feat + (size_t)M_SEQ * 8;              // (M,)
    int*   cbuf  = (int*)(vbuf + M_SEQ);                  // (M,)
    float* bufA  = (float*)(cbuf + M_SEQ);                // (CHUNK,64,16)
    float* bufB  = bufA + (size_t)CHUNK * TT * 16;        // (CHUNK,64,16)
    float* xgbuf = bufB + (size_t)CHUNK * TT * 16;        // (CHUNK,2,64,24)

    const dim3 gx(CHUNK * TT / 256, 2);
    const int  grec = CHUNK * 2 * 8 / 256;
    for (int cs = 0; cs < M_SEQ; cs += CHUNK) {
        const float* x0 = full_seq + (size_t)cs * TT * 8;
        // layer 0 (I=8): full_seq -> bufA
        gru_xg<8><<<gx, 256, 0, stream>>>(x0, g0wih, g0bih, xgbuf, CHUNK);
        gru_rec<<<grec, 256, 0, stream>>>(xgbuf, g0whh, g0bhh, bufA, CHUNK);
        // layers 1..3 (I=16): ping-pong bufA<->bufB
        float* src = bufA; float* dst = bufB;
        for (int l = 0; l < 3; ++l) {
            gru_xg<16><<<gx, 256, 0, stream>>>(src, gwih + l * 768, gbih + l * 48,
                                               xgbuf, CHUNK);
            gru_rec<<<grec, 256, 0, stream>>>(xgbuf, gwhh + l * 384, gbhh + l * 48,
                                              dst, CHUNK);
            float* tmp = src; src = dst; dst = tmp;
        }
        // after 3 swaps the final output is in src (= bufB)
        feat_kernel<<<CHUNK / 256, 256, 0, stream>>>(src, l1w, l1b, l2w, l2b,
                                                     feat + (size_t)cs * 8, CHUNK);
    }
    adj_kernel<<<(NB * NNODE) / 4, 256, 0, stream>>>(feat, temp, cbuf, vbuf);
    decode_kernel<<<NB, 384, 0, stream>>>(rec_seq, cbuf, vbuf,
                                          enc_gw, enc_gb, enc_cw, enc_cb,
                                          dec_gw, dec_gb, dec_cw, dec_cb,
                                          proj_w, proj_b, outp);
}

// Round 7
// 681.374 us; speedup vs baseline: 6.0119x; 1.6366x over previous
//
#include <hip/hip_runtime.h>
#include <math.h>

#define M_SEQ 11520   // B*N
#define NNODE 360
#define NB    32
#define TT    64

// GRU/feat/adj path: libm-accurate (feeds the precision-fragile argmax).
__device__ __forceinline__ float fsig(float x)  { return 1.0f / (1.0f + expf(-x)); }
__device__ __forceinline__ float ftanh(float x) { return tanhf(x); }
// Decode path: post-argmax, fast hardware exp (v_exp). Drift budget ~4e-5.
__device__ __forceinline__ float fsigd(float x)  { return 1.0f / (1.0f + __expf(-x)); }
__device__ __forceinline__ float ftanhd(float x) { return 1.0f - 2.0f / (__expf(2.0f * x) + 1.0f); }

// ---------------- JAX threefry2x32, key=(0,42), partitionable, bits=y0^y1 ----
__device__ __forceinline__ unsigned rotl32(unsigned x, int n) { return (x << n) | (x >> (32 - n)); }

__device__ __forceinline__ void tf2x32(unsigned& x0, unsigned& x1)
{
    const unsigned k0 = 0u, k1 = 42u, k2 = 0u ^ 42u ^ 0x1BD11BDAu;
    x0 += k0; x1 += k1;
#define R4(a,b,c,d) \
    x0 += x1; x1 = rotl32(x1,a); x1 ^= x0; \
    x0 += x1; x1 = rotl32(x1,b); x1 ^= x0; \
    x0 += x1; x1 = rotl32(x1,c); x1 ^= x0; \
    x0 += x1; x1 = rotl32(x1,d); x1 ^= x0;
    R4(13,15,26,6)   x0 += k1; x1 += k2 + 1u;
    R4(17,29,16,24)  x0 += k2; x1 += k0 + 2u;
    R4(13,15,26,6)   x0 += k0; x1 += k1 + 3u;
    R4(17,29,16,24)  x0 += k1; x1 += k2 + 4u;
    R4(13,15,26,6)   x0 += k2; x1 += k0 + 5u;
#undef R4
}

__device__ __forceinline__ float jax_uniform(unsigned idx)
{
    unsigned x0 = 0u, x1 = idx;       // counts_hi=0, counts_lo=idx
    tf2x32(x0, x1);
    unsigned bits = x0 ^ x1;          // VERIFIED R5: jax partitionable = bits1^bits2
    return __uint_as_float((bits >> 9) | 0x3f800000u) - 1.0f;
}

// ---------------- fused bidirectional GRU layer -----------------------------
// 8 lanes per (m,dir); lane j holds Wih rows {j,8+j,16+j} and Whh gate rows
// in VGPRs; x-gates computed inline (h-independent -> fills recurrence stalls);
// h broadcast via __shfl. Replaces the gru_xg+gru_rec pair (no xg HBM trip).
template<int I>
__global__ __launch_bounds__(256) void gru_fused(
    const float* __restrict__ x,    // (M,64,I)
    const float* __restrict__ wih,  // (2,24,I)
    const float* __restrict__ whh,  // (2,24,8)
    const float* __restrict__ bih,  // (2,24)
    const float* __restrict__ bhh,  // (2,24)
    float* __restrict__ out)        // (M,64,16), dir writes its 8-half
{
    const int tid = blockIdx.x * 256 + threadIdx.x;
    const int j   = tid & 7;
    const int md  = tid >> 3;
    if (md >= M_SEQ * 2) return;
    const int m = md >> 1, dir = md & 1;
    const int lane_base = (threadIdx.x & 63) & ~7;

    float wx0[I], wx1[I], wx2[I];
    const float* WI = wih + dir * 24 * I;
#pragma unroll
    for (int k = 0; k < I; ++k) {
        wx0[k] = WI[j * I + k];
        wx1[k] = WI[(8 + j) * I + k];
        wx2[k] = WI[(16 + j) * I + k];
    }
    float w0[8], w1[8], w2[8];
    const float* WH = whh + dir * 192;
#pragma unroll
    for (int k = 0; k < 8; ++k) {
        w0[k] = WH[j * 8 + k];
        w1[k] = WH[(8 + j) * 8 + k];
        w2[k] = WH[(16 + j) * 8 + k];
    }
    const float bx0 = bih[dir*24 + j], bx1 = bih[dir*24 + 8 + j], bx2 = bih[dir*24 + 16 + j];
    const float bh0 = bhh[dir*24 + j], bh1 = bhh[dir*24 + 8 + j], bh2 = bhh[dir*24 + 16 + j];

    const float* xm = x + (size_t)m * TT * I;
    float* om = out + (size_t)m * TT * 16 + dir * 8 + j;

    float h = 0.f;
    for (int tt = 0; tt < TT; ++tt) {
        const int t = dir ? (TT - 1 - tt) : tt;
        float xv[I];
        const float4* xp4 = reinterpret_cast<const float4*>(xm + t * I);
#pragma unroll
        for (int q = 0; q < I / 4; ++q) {
            float4 f = xp4[q];
            xv[4*q] = f.x; xv[4*q+1] = f.y; xv[4*q+2] = f.z; xv[4*q+3] = f.w;
        }
        float xr = bx0, xz = bx1, xn = bx2;
#pragma unroll
        for (int k = 0; k < I; ++k) {
            xr += xv[k] * wx0[k];
            xz += xv[k] * wx1[k];
            xn += xv[k] * wx2[k];
        }
        float gh0 = bh0, gh1 = bh1, gh2 = bh2;
#pragma unroll
        for (int k = 0; k < 8; ++k) {
            float hk = __shfl(h, lane_base + k, 64);
            gh0 += hk * w0[k];
            gh1 += hk * w1[k];
            gh2 += hk * w2[k];
        }
        float r  = fsig(xr + gh0);
        float z  = fsig(xz + gh1);
        float nn = ftanh(xn + r * gh2);
        h = (1.f - z) * nn + z * h;
        om[t * 16] = h;
    }
}

// ---------------- feat MLP ---------------------------------------------------
__global__ void feat_kernel(const float* __restrict__ gout,
                            const float* __restrict__ l1w, const float* __restrict__ l1b,
                            const float* __restrict__ l2w, const float* __restrict__ l2b,
                            float* __restrict__ feat)
{
    int m = blockIdx.x * blockDim.x + threadIdx.x;
    if (m >= M_SEQ) return;
    const float* xp = gout + (size_t)m * TT * 16 + (TT - 1) * 16;
    float xv[16];
#pragma unroll
    for (int i = 0; i < 16; ++i) xv[i] = xp[i];
    float h1[8];
#pragma unroll
    for (int o = 0; o < 8; ++o) {
        float a = 0.f;
#pragma unroll
        for (int f = 0; f < 16; ++f) a += xv[f] * l1w[o * 16 + f];
        a += l1b[o];
        h1[o] = (a >= 0.f) ? a : 0.2f * a;
    }
#pragma unroll
    for (int o = 0; o < 8; ++o) {
        float a = 0.f;
#pragma unroll
        for (int f = 0; f < 8; ++f) a += h1[f] * l2w[o * 8 + f];
        feat[(size_t)m * 8 + o] = a + l2b[o];
    }
}

// ---------------- adjacency: per row -> (argmax col, adj value v) -----------
__global__ void adj_kernel(const float* __restrict__ feat,
                           const float* __restrict__ tptr,
                           int* __restrict__ colp, float* __restrict__ vp)
{
    const int gw   = (blockIdx.x * blockDim.x + threadIdx.x) >> 6;
    const int lane = threadIdx.x & 63;
    if (gw >= NB * NNODE) return;
    const int b = gw / NNODE;
    const int n = gw - b * NNODE;
    const float T = tptr[0];
    const float* fb = feat + (size_t)b * NNODE * 8;
    float fn[8];
#pragma unroll
    for (int k = 0; k < 8; ++k) fn[k] = fb[(size_t)n * 8 + k];

    float sv[6];
    float mval = -3.0e38f; int midx = 1 << 30;
#pragma unroll
    for (int s = 0; s < 6; ++s) {
        int p = s * 64 + lane;
        float xs = -3.0e38f;
        if (p < NNODE) {
            const float* fp = fb + (size_t)p * 8;
            float d = 0.f;
#pragma unroll
            for (int k = 0; k < 8; ++k) d += fn[k] * fp[k];
            unsigned idx = (unsigned)gw * 360u + (unsigned)p;
            float u   = jax_uniform(idx);
            float gum = -logf(-logf(u + 1e-10f) + 1e-10f);
            xs = (d + gum) / T;
            if (xs > mval) { mval = xs; midx = p; }
        }
        sv[s] = xs;
    }
    for (int off = 32; off > 0; off >>= 1) {   // ties -> smaller index
        float ov = __shfl_xor(mval, off);
        int   oi = __shfl_xor(midx, off);
        if (ov > mval || (ov == mval && oi < midx)) { mval = ov; midx = oi; }
    }
    float ssum = 0.f;
#pragma unroll
    for (int s = 0; s < 6; ++s) {
        int p = s * 64 + lane;
        if (p < NNODE) ssum += expf(sv[s] - mval);
    }
    for (int off = 32; off > 0; off >>= 1) ssum += __shfl_xor(ssum, off);
    if (lane == 0) {
        float ys = 1.0f / ssum;
        float v  = ys + (1.0f - ys);
        if (midx == n) v = 0.0f;
        colp[gw] = midx;
        vp[gw]   = v;
    }
}

// ---------------- DCGRU 3-layer step, 3 barriers total ----------------------
// Functional-graph closure: adj has one nonzero/row, so node n's dependency
// set is the chain n, c(n), c2(n), ... The rh mid-barrier is eliminated by
// redundantly computing r at c(n), c2(n) locally (gathers extend to c4(n)) —
// identical formula to what threads c1/c2 compute, so numerically equivalent.
// o-buffers: fixed 0 -> 1 -> 2 (input in 0); h double-buffered on step parity.
__device__ __forceinline__ float dc_step3(
    float (*s_o)[NNODE], float (*s_h)[2][NNODE], int p,
    const float* Wg, const float* Bg, const float* Wc, const float* Cb,
    bool act, int n, const int* cc, const float* vL, const float* wv)
{
    float h3 = 0.f;
    for (int l = 0; l < 3; ++l) {
        __syncthreads();   // input/o-buffer and h[l][p] ready
        float o0 = s_o[l][cc[0]], o1 = s_o[l][cc[1]], o2 = s_o[l][cc[2]],
              o3 = s_o[l][cc[3]], o4 = s_o[l][cc[4]];
        float h0 = s_h[l][p][cc[0]], h1 = s_h[l][p][cc[1]], h2 = s_h[l][p][cc[2]],
              h3g = s_h[l][p][cc[3]], h4 = s_h[l][p][cc[4]];
        const float* W = Wg + l * 12;
        const float bgr = Bg[l * 2], bgu = Bg[l * 2 + 1];
        // gates at n (k=0)
        float f1 = vL[0]*o1, f2 = wv[0]*o2 - o0, f4 = vL[0]*h1, f5 = wv[0]*h2 - h0;
        float r0 = fsigd(o0*W[0] + f1*W[2] + f2*W[4] + h0*W[6] + f4*W[8] + f5*W[10] + bgr);
        float u0 = fsigd(o0*W[1] + f1*W[3] + f2*W[5] + h0*W[7] + f4*W[9] + f5*W[11] + bgu);
        // redundant r at c1 (k=1) and c2 (k=2)
        float a1 = vL[1]*o2, b1 = wv[1]*o3 - o1, c1f = vL[1]*h2, d1 = wv[1]*h3g - h1;
        float r1 = fsigd(o1*W[0] + a1*W[2] + b1*W[4] + h1*W[6] + c1f*W[8] + d1*W[10] + bgr);
        float a2 = vL[2]*o3, b2 = wv[2]*o4 - o2, c2f = vL[2]*h3g, d2 = wv[2]*h4 - h2;
        float r2 = fsigd(o2*W[0] + a2*W[2] + b2*W[4] + h2*W[6] + c2f*W[8] + d2*W[10] + bgr);
        float rh0 = r0 * h0, rh1 = r1 * h1, rh2 = r2 * h2;
        const float* C = Wc + l * 6;
        float cnd = ftanhd(o0*C[0] + f1*C[1] + f2*C[2]
                           + rh0*C[3] + (vL[0]*rh1)*C[4] + (wv[0]*rh2 - rh0)*C[5] + Cb[l]);
        float hnew = u0 * h0 + (1.f - u0) * cnd;
        if (act) {
            s_h[l][p ^ 1][n] = hnew;
            if (l < 2) s_o[l + 1][n] = hnew;
        }
        h3 = hnew;
    }
    return h3;
}

__global__ __launch_bounds__(384) void decode_kernel(
    const float* __restrict__ rec,   // (B, N, T)
    const int*   __restrict__ colp, const float* __restrict__ vp,
    const float* __restrict__ egw, const float* __restrict__ egb,
    const float* __restrict__ ecw, const float* __restrict__ ecb,
    const float* __restrict__ dgw, const float* __restrict__ dgb,
    const float* __restrict__ dcw, const float* __restrict__ dcb,
    const float* __restrict__ pw,  const float* __restrict__ pb,
    float* __restrict__ outp)        // (B, N, T)
{
    __shared__ float s_o[3][NNODE];
    __shared__ float s_h[3][2][NNODE];
    __shared__ float s_v[NNODE];
    __shared__ int   s_c[NNODE];
    __shared__ float s_egw[36], s_egb[6], s_ecw[18], s_ecb[3];
    __shared__ float s_dgw[36], s_dgb[6], s_dcw[18], s_dcb[3];

    const int b = blockIdx.x;
    const int n = threadIdx.x;
    if (n < 36) { s_egw[n] = egw[n]; s_dgw[n] = dgw[n]; }
    if (n < 6)  { s_egb[n] = egb[n]; s_dgb[n] = dgb[n]; }
    if (n < 18) { s_ecw[n] = ecw[n]; s_dcw[n] = dcw[n]; }
    if (n < 3)  { s_ecb[n] = ecb[n]; s_dcb[n] = dcb[n]; }
    const bool act = n < NNODE;
    if (act) {
        s_c[n] = colp[b * NNODE + n];
        s_v[n] = vp[b * NNODE + n];
        s_h[0][0][n] = 0.f; s_h[1][0][n] = 0.f; s_h[2][0][n] = 0.f;
    }
    __syncthreads();
    int   cc[5] = {0, 0, 0, 0, 0};
    float vL[3] = {0.f, 0.f, 0.f}, wv[3] = {0.f, 0.f, 0.f};
    if (act) {
        cc[0] = n; cc[1] = s_c[cc[0]]; cc[2] = s_c[cc[1]];
        cc[3] = s_c[cc[2]]; cc[4] = s_c[cc[3]];
        float v0 = s_v[cc[0]], v1 = s_v[cc[1]], v2 = s_v[cc[2]], v3 = s_v[cc[3]];
        vL[0] = v0; vL[1] = v1; vL[2] = v2;
        wv[0] = 2.f * v0 * v1; wv[1] = 2.f * v1 * v2; wv[2] = 2.f * v2 * v3;
    }
    const float projw = pw[0], projb = pb[0];
    int p = 0;

    // encoder (input prefetched one step ahead to hide the strided global read)
    float inp = act ? rec[((size_t)b * NNODE + n) * TT + 0] : 0.f;
    for (int t = 0; t < TT; ++t) {
        float inp_nxt = (act && t + 1 < TT) ? rec[((size_t)b * NNODE + n) * TT + t + 1] : 0.f;
        if (act) s_o[0][n] = inp;
        dc_step3(s_o, s_h, p, s_egw, s_egb, s_ecw, s_ecb, act, n, cc, vL, wv);
        p ^= 1;
        inp = inp_nxt;
    }
    // decoder (feedback = proj of own h3; gathers see all projs via s_o)
    float dinp = 0.f;
    for (int t = 0; t < TT; ++t) {
        if (act) s_o[0][n] = dinp;
        float h3 = dc_step3(s_o, s_h, p, s_dgw, s_dgb, s_dcw, s_dcb, act, n, cc, vL, wv);
        p ^= 1;
        float proj = h3 * projw + projb;
        if (act) outp[((size_t)b * NNODE + n) * TT + t] = proj;
        dinp = proj;
    }
}

// ---------------- host launcher ---------------------------------------------
extern "C" void kernel_launch(void* const* d_in, const int* in_sizes, int n_in,
                              void* d_out, int out_size, void* d_ws, size_t ws_size,
                              hipStream_t stream)
{
    (void)in_sizes; (void)n_in; (void)out_size; (void)ws_size;
    const float* full_seq = (const float*)d_in[0];   // (M,64,8)
    const float* rec_seq  = (const float*)d_in[1];   // (32,360,64)
    const float* temp     = (const float*)d_in[3];
    const float* g0wih    = (const float*)d_in[4];
    const float* g0whh    = (const float*)d_in[5];
    const float* g0bih    = (const float*)d_in[6];
    const float* g0bhh    = (const float*)d_in[7];
    const float* gwih     = (const float*)d_in[8];   // (3,2,24,16)
    const float* gwhh     = (const float*)d_in[9];   // (3,2,24,8)
    const float* gbih     = (const float*)d_in[10];
    const float* gbhh     = (const float*)d_in[11];
    const float* l1w      = (const float*)d_in[12];
    const float* l1b      = (const float*)d_in[13];
    const float* l2w      = (const float*)d_in[14];
    const float* l2b      = (const float*)d_in[15];
    const float* enc_gw   = (const float*)d_in[16];
    const float* enc_gb   = (const float*)d_in[17];
    const float* enc_cw   = (const float*)d_in[18];
    const float* enc_cb   = (const float*)d_in[19];
    const float* dec_gw   = (const float*)d_in[20];
    const float* dec_gb   = (const float*)d_in[21];
    const float* dec_cw   = (const float*)d_in[22];
    const float* dec_cb   = (const float*)d_in[23];
    const float* proj_w   = (const float*)d_in[24];
    const float* proj_b   = (const float*)d_in[25];
    float* outp = (float*)d_out;

    // ws: small-first; bufA+bufB ping-pong = 94.85 MB total (== R1's proven layout)
    float* ws   = (float*)d_ws;
    float* feat = ws;                                     // (M,8)
    float* vbuf = feat + (size_t)M_SEQ * 8;               // (M,)
    int*   cbuf = (int*)(vbuf + M_SEQ);                   // (M,)
    float* bufA = (float*)(cbuf + M_SEQ);                 // (M,64,16)
    float* bufB = bufA + (size_t)M_SEQ * TT * 16;         // (M,64,16)

    const int ggru = (M_SEQ * 2 * 8) / 256;   // 720 blocks
    gru_fused<8><<<ggru, 256, 0, stream>>>(full_seq, g0wih, g0whh, g0bih, g0bhh, bufA);
    gru_fused<16><<<ggru, 256, 0, stream>>>(bufA, gwih + 0 * 768, gwhh + 0 * 384,
                                            gbih + 0 * 48, gbhh + 0 * 48, bufB);
    gru_fused<16><<<ggru, 256, 0, stream>>>(bufB, gwih + 1 * 768, gwhh + 1 * 384,
                                            gbih + 1 * 48, gbhh + 1 * 48, bufA);
    gru_fused<16><<<ggru, 256, 0, stream>>>(bufA, gwih + 2 * 768, gwhh + 2 * 384,
                                            gbih + 2 * 48, gbhh + 2 * 48, bufB);
    feat_kernel<<<M_SEQ / 256, 256, 0, stream>>>(bufB, l1w, l1b, l2w, l2b, feat);
    adj_kernel<<<(NB * NNODE) / 4, 256, 0, stream>>>(feat, temp, cbuf, vbuf);
    decode_kernel<<<NB, 384, 0, stream>>>(rec_seq, cbuf, vbuf,
                                          enc_gw, enc_gb, enc_cw, enc_cb,
                                          dec_gw, dec_gb, dec_cw, dec_cb,
                                          proj_w, proj_b, outp);
}